// Round 8
// baseline (185.690 us; speedup 1.0000x reference)
//
#include <hip/hip_runtime.h>
#include <hip/hip_bf16.h>
#include <math.h>

#define BATCH 8
#define CIN   512
#define DQKV  768
#define NHEAD 8
#define HW    1024

typedef __attribute__((ext_vector_type(8))) short  short8;
typedef __attribute__((ext_vector_type(4))) float  float4v;

__device__ __forceinline__ ushort f2bf(float f) {
    union { float f; unsigned u; } c; c.f = f;
    unsigned u = c.u + 0x7fffu + ((c.u >> 16) & 1u);   // RNE
    return (ushort)(u >> 16);
}

// packed 2x fp32 -> bf16 (RNE), low = a
__device__ __forceinline__ uint pkbf(float a, float b) {
    union { __hip_bfloat162 h; uint u; } c;
    c.h = __float22bfloat162_rn(make_float2(a, b));
    return c.u;
}

__device__ __forceinline__ void async_ld16(const ushort* g, ushort* l) {
    auto gp = (const __attribute__((address_space(1))) unsigned int*)g;
    auto lp = (__attribute__((address_space(3))) unsigned int*)l;
    __builtin_amdgcn_global_load_lds(gp, lp, 16, 0, 0);
}

// ---------------------------------------------------------------------------
// Transpose + fp32->bf16: per batch, in [K][N] fp32 -> out [N][K] bf16.
// ---------------------------------------------------------------------------
__global__ __launch_bounds__(256)
void transpose_cvt(const float* __restrict__ in, ushort* __restrict__ out,
                   int K, int N)
{
    __shared__ float Ts[64][65];
    const int b  = blockIdx.z;
    const int k0 = blockIdx.y * 64;
    const int n0 = blockIdx.x * 64;
    const int t  = threadIdx.x;
    const float* ib = in + (size_t)b * K * N;
    ushort*      ob = out + (size_t)b * N * K;

    const int r  = t >> 4;
    const int c4 = (t & 15) * 4;
    #pragma unroll
    for (int p = 0; p < 4; ++p) {
        float4 v = *(const float4*)(ib + (size_t)(k0 + r + 16 * p) * N + n0 + c4);
        Ts[r + 16 * p][c4 + 0] = v.x;
        Ts[r + 16 * p][c4 + 1] = v.y;
        Ts[r + 16 * p][c4 + 2] = v.z;
        Ts[r + 16 * p][c4 + 3] = v.w;
    }
    __syncthreads();

    const int nl = t >> 3;
    const int kc = (t & 7) * 8;
    #pragma unroll
    for (int p = 0; p < 2; ++p) {
        int n = nl + 32 * p;
        uint4 u;
        u.x = pkbf(Ts[kc + 0][n], Ts[kc + 1][n]);
        u.y = pkbf(Ts[kc + 2][n], Ts[kc + 3][n]);
        u.z = pkbf(Ts[kc + 4][n], Ts[kc + 5][n]);
        u.w = pkbf(Ts[kc + 6][n], Ts[kc + 7][n]);
        *(uint4*)(ob + (size_t)(n0 + n) * K + k0 + kc) = u;
    }
}

// elementwise fp32 -> bf16 (weights), 8 elems/thread
__global__ void cvt_bf16(const float* __restrict__ in, ushort* __restrict__ out, int n8)
{
    int i = blockIdx.x * blockDim.x + threadIdx.x;
    if (i >= n8) return;
    const float4* p = (const float4*)(in + (size_t)i * 8);
    float4 a = p[0], b = p[1];
    uint4 u;
    u.x = pkbf(a.x, a.y);
    u.y = pkbf(a.z, a.w);
    u.z = pkbf(b.x, b.y);
    u.w = pkbf(b.z, b.w);
    *(uint4*)(out + (size_t)i * 8) = u;
}

// ---------------------------------------------------------------------------
// bf16 MFMA GEMM (m97 structure).
// OUTMODE 0: fp32 natural O[b][m][n].
// OUTMODE 2: qkv split — m0<512: transposed bf16 into Qt/Kt[b][head][sp][32d]
//            (LDS-staged, coalesced); m0>=512: bf16 natural into vb[b][m-512][n].
// ---------------------------------------------------------------------------
#define TEW 136    // epilogue transpose tile row stride (shorts)

template<int M, int K, bool QSCALE, int OUTMODE>
__global__ __launch_bounds__(256, 2)
void gemm_bt(const ushort* __restrict__ A, const ushort* __restrict__ Bt,
             const float* __restrict__ bias, void* __restrict__ Oo,
             ushort* __restrict__ qt, ushort* __restrict__ kt)
{
    __shared__ __align__(16) ushort SH[16384];
    ushort* As = SH;
    ushort* Bs = SH + 8192;

    const int b    = blockIdx.z;
    const int m0   = blockIdx.y * 128;
    const int n0   = blockIdx.x * 128;
    const int t    = threadIdx.x;
    const int lane = t & 63;
    const int wave = t >> 6;
    const int l16  = lane & 15;
    const int quad = lane >> 4;
    const int wm   = (wave & 1) * 64;
    const int wn   = (wave >> 1) * 64;

    const ushort* Bb = Bt + (size_t)b * HW * K;

    float4v acc[4][4];
    #pragma unroll
    for (int i = 0; i < 4; ++i)
        #pragma unroll
        for (int j = 0; j < 4; ++j)
            acc[i][j] = (float4v){0.f, 0.f, 0.f, 0.f};

    const int srow = t >> 3;
    const int sg   = t & 7;

    for (int k0 = 0; k0 < K; k0 += 64) {
        __syncthreads();
        #pragma unroll
        for (int is = 0; is < 4; ++is) {
            int row = srow + is * 32;
            int gch = sg ^ (row & 7);
            async_ld16(A  + (size_t)(m0 + row) * K + k0 + gch * 8,
                       As + (size_t)t * 8 + is * 2048);
            async_ld16(Bb + (size_t)(n0 + row) * K + k0 + gch * 8,
                       Bs + (size_t)t * 8 + is * 2048);
        }
        __syncthreads();

        #pragma unroll
        for (int ks = 0; ks < 2; ++ks) {
            short8 af[4], bf[4];
            #pragma unroll
            for (int i = 0; i < 4; ++i) {
                int row = wm + i * 16 + l16;
                int ch  = (ks * 4 + quad) ^ (row & 7);
                af[i] = *(const short8*)&As[row * 64 + ch * 8];
            }
            #pragma unroll
            for (int j = 0; j < 4; ++j) {
                int row = wn + j * 16 + l16;
                int ch  = (ks * 4 + quad) ^ (row & 7);
                bf[j] = *(const short8*)&Bs[row * 64 + ch * 8];
            }
            #pragma unroll
            for (int i = 0; i < 4; ++i)
                #pragma unroll
                for (int j = 0; j < 4; ++j)
                    acc[i][j] = __builtin_amdgcn_mfma_f32_16x16x32_bf16(
                        af[i], bf[j], acc[i][j], 0, 0, 0);
        }
    }

    if (OUTMODE == 2 && m0 < 512) {
        // ---- transposed epilogue -> Qt/Kt[b][head][sp][32d] ----
        ushort* dst = (m0 < 256) ? qt : kt;
        const int headbase = (m0 & 255) >> 5;                 // 0 or 4
        const float sc = (QSCALE && m0 < 256) ? 0.17677669529663687f : 1.0f;
        #pragma unroll
        for (int hn = 0; hn < 2; ++hn) {
            __syncthreads();
            if ((wave >> 1) == hn) {
                #pragma unroll
                for (int i = 0; i < 4; ++i) {
                    int m_l = wm + i * 16 + quad * 4;
                    float bi[4];
                    #pragma unroll
                    for (int rr = 0; rr < 4; ++rr) bi[rr] = bias[m0 + m_l + rr];
                    #pragma unroll
                    for (int j = 0; j < 4; ++j) {
                        int n_l = j * 16 + l16;               // 0..63 within half
                        uint2 pk;
                        pk.x = pkbf((acc[i][j][0] + bi[0]) * sc,
                                    (acc[i][j][1] + bi[1]) * sc);
                        pk.y = pkbf((acc[i][j][2] + bi[2]) * sc,
                                    (acc[i][j][3] + bi[3]) * sc);
                        *(uint2*)&SH[n_l * TEW + m_l] = pk;
                    }
                }
            }
            __syncthreads();
            #pragma unroll
            for (int p = 0; p < 4; ++p) {
                int idx = p * 256 + t;
                int d8 = idx & 3, h_l = (idx >> 2) & 3, n_l = idx >> 4;
                uint4 u = *(const uint4*)&SH[n_l * TEW + h_l * 32 + d8 * 8];
                size_t a = ((size_t)(b * NHEAD + headbase + h_l) * HW
                            + (n0 + hn * 64 + n_l)) * 32 + d8 * 8;
                *(uint4*)(dst + a) = u;
            }
        }
    } else {
        #pragma unroll
        for (int i = 0; i < 4; ++i) {
            #pragma unroll
            for (int rr = 0; rr < 4; ++rr) {
                int m = m0 + wm + i * 16 + quad * 4 + rr;
                float bi = bias[m];
                #pragma unroll
                for (int j = 0; j < 4; ++j) {
                    int n = n0 + wn + j * 16 + l16;
                    float val = acc[i][j][rr] + bi;
                    if (OUTMODE == 2)
                        ((ushort*)Oo)[((size_t)b * 256 + (m & 255)) * HW + n] = f2bf(val);
                    else
                        ((float*)Oo)[((size_t)b * M + m) * HW + n] = val;
                }
            }
        }
    }
}

// ---------------------------------------------------------------------------
// MFMA attention core v7 — k-split for TLP.
// Block = (b, j, uh, split s): q-set = { (uh*16+ui)*32 + j }, k in
// [s*512, s*512+512) as 4 tiles of 128. Grid 1024 blocks -> 4 blocks/CU
// co-resident (LDS cap), staggered phases hide the per-iter latency chain.
// Softmax is pointwise in k (head axis) -> k-chunks fully independent;
// partial O accumulated fp32 into pb[s], reduced by reduce_ab.
// ---------------------------------------------------------------------------
#define WROW 136   // Ws row stride (shorts)
#define OROWF 132  // fp32 epilogue row stride (floats)

__global__ __launch_bounds__(512, 8)
void attn_kernel(const ushort* __restrict__ vb, const ushort* __restrict__ Qt,
                 const ushort* __restrict__ Kt, float* __restrict__ pb)
{
    __shared__ __align__(16) ushort Ws[NHEAD * 16 * WROW];   // 34816 B

    const int t    = threadIdx.x;
    const int b    = blockIdx.y;
    const int s    = blockIdx.z;           // k-split index
    const int j    = blockIdx.x >> 1;      // hw-row group (q & 31)
    const int uh   = blockIdx.x & 1;       // u half
    const int wave = t >> 6;               // logits: k-chunk; PV: head
    const int lane = t & 63;
    const int l16  = lane & 15;
    const int quad = lane >> 4;
    const int kbase = s * 512;

    const ushort* Vb  = vb + (size_t)b * 256 * HW;
    const ushort* Qtb = Qt + (size_t)b * (NHEAD * HW * 32);
    const ushort* Ktb = Kt + (size_t)b * (NHEAD * HW * 32);

    // ---- preload Q B-frags: lane l16 = ui -> q = (uh*16+ui)*32 + j ----
    const int qlane = (uh * 16 + l16) * 32 + j;
    short8 qf[NHEAD];
    #pragma unroll
    for (int h = 0; h < NHEAD; ++h)
        qf[h] = *(const short8*)(Qtb + ((size_t)h * HW + qlane) * 32 + quad * 8);

    // logits tile -> softmax -> packed bf16 weights (pure registers)
    auto compute_wpk = [&](int k0, uint2* wpk) {
        const int kk = k0 + wave * 16 + l16;
        float4v S[NHEAD];
        #pragma unroll
        for (int h = 0; h < NHEAD; ++h) {
            short8 kf = *(const short8*)(Ktb + ((size_t)h * HW + kk) * 32 + quad * 8);
            S[h] = __builtin_amdgcn_mfma_f32_16x16x32_bf16(
                kf, qf[h], (float4v){0.f, 0.f, 0.f, 0.f}, 0, 0, 0);
        }
        float4v mx = S[0];
        #pragma unroll
        for (int h = 1; h < NHEAD; ++h)
            #pragma unroll
            for (int r = 0; r < 4; ++r) mx[r] = fmaxf(mx[r], S[h][r]);
        float4v sum = (float4v){0.f, 0.f, 0.f, 0.f};
        #pragma unroll
        for (int h = 0; h < NHEAD; ++h)
            #pragma unroll
            for (int r = 0; r < 4; ++r) {
                S[h][r] = __expf(S[h][r] - mx[r]);
                sum[r] += S[h][r];
            }
        float4v inv;
        #pragma unroll
        for (int r = 0; r < 4; ++r) inv[r] = __builtin_amdgcn_rcpf(sum[r]);
        #pragma unroll
        for (int h = 0; h < NHEAD; ++h) {
            wpk[h].x = pkbf(S[h][0] * inv[0], S[h][1] * inv[1]);
            wpk[h].y = pkbf(S[h][2] * inv[2], S[h][3] * inv[3]);
        }
    };

    float4v oacc[2];
    oacc[0] = (float4v){0.f, 0.f, 0.f, 0.f};
    oacc[1] = (float4v){0.f, 0.f, 0.f, 0.f};

    // prologue: weights for tile 0
    {
        uint2 w0[NHEAD];
        compute_wpk(kbase, w0);
        #pragma unroll
        for (int h = 0; h < NHEAD; ++h)
            *(uint2*)&Ws[(size_t)(h * 16 + l16) * WROW + wave * 16 + quad * 4] = w0[h];
    }
    __syncthreads();

    for (int i = 0; i < 4; ++i) {
        const int k0 = kbase + i * 128;

        uint2 nxt[NHEAD];
        if (i < 3) compute_wpk(k0 + 128, nxt);   // independent of PV below

        // ---- PV on tile i: head = wave; O[ui][d] += W[ui][k] V[d][k] ----
        #pragma unroll
        for (int ks = 0; ks < 4; ++ks) {
            short8 wf = *(const short8*)&Ws[(size_t)(wave * 16 + l16) * WROW + ks * 32 + quad * 8];
            #pragma unroll
            for (int ds = 0; ds < 2; ++ds) {
                short8 vf = *(const short8*)(Vb + (size_t)(wave * 32 + ds * 16 + l16) * HW
                                             + k0 + ks * 32 + quad * 8);
                oacc[ds] = __builtin_amdgcn_mfma_f32_16x16x32_bf16(wf, vf, oacc[ds], 0, 0, 0);
            }
        }

        if (i < 3) {
            __syncthreads();   // PV done reading Ws
            #pragma unroll
            for (int h = 0; h < NHEAD; ++h)
                *(uint2*)&Ws[(size_t)(h * 16 + l16) * WROW + wave * 16 + quad * 4] = nxt[h];
            __syncthreads();   // Ws ready
        }
    }

    // ---- epilogue: stage fp32 O in LDS [d][local c = h*16+ui], write pb ----
    __syncthreads();
    float* Ot = (float*)Ws;                 // 32 * OROWF floats = 16896 B
    #pragma unroll
    for (int ds = 0; ds < 2; ++ds) {
        int d = ds * 16 + l16;
        *(float4*)&Ot[(size_t)d * OROWF + wave * 16 + quad * 4] =
            make_float4(oacc[ds][0], oacc[ds][1], oacc[ds][2], oacc[ds][3]);
    }
    __syncthreads();

    // pb[s][b][hw = j*32+d][c = h*32 + uh*16 + cc]
    #pragma unroll
    for (int p = 0; p < 2; ++p) {
        int idx = p * 512 + t;              // 0..1023 over 32d x 32 chunks
        int d  = idx >> 5;
        int u  = idx & 31;
        int h  = u >> 2;
        int c4 = (u & 3) * 4;
        float4 v = *(const float4*)&Ot[(size_t)d * OROWF + h * 16 + c4];
        size_t addr = (((size_t)s * BATCH + b) * HW + j * 32 + d) * 256
                    + h * 32 + uh * 16 + c4;
        *(float4*)(pb + addr) = v;
    }
}

// ---------------------------------------------------------------------------
// reduce_ab: ab[i] = bf16(pb[0][i] + pb[1][i]), 4 elems/thread.
// ---------------------------------------------------------------------------
__global__ __launch_bounds__(512)
void reduce_ab(const float* __restrict__ pb, ushort* __restrict__ ab)
{
    const size_t n = (size_t)BATCH * HW * 256;
    size_t i = ((size_t)blockIdx.x * 512 + threadIdx.x) * 4;
    float4 a = *(const float4*)(pb + i);
    float4 b = *(const float4*)(pb + n + i);
    uint2 u;
    u.x = pkbf(a.x + b.x, a.y + b.y);
    u.y = pkbf(a.z + b.z, a.w + b.w);
    *(uint2*)(ab + i) = u;
}

// ---------------------------------------------------------------------------
extern "C" void kernel_launch(void* const* d_in, const int* in_sizes, int n_in,
                              void* d_out, int out_size, void* d_ws, size_t ws_size,
                              hipStream_t stream)
{
    const float* x      = (const float*)d_in[0];
    const float* w_qkv  = (const float*)d_in[1];
    const float* b_qkv  = (const float*)d_in[2];
    const float* w_attn = (const float*)d_in[3];
    const float* b_attn = (const float*)d_in[4];
    float* out = (float*)d_out;

    // workspace (33 MB): vb | Qt | Kt | ab | wb1 | wb2 | xb | pb (pb aliases xb)
    ushort* vb  = (ushort*)d_ws;                   // 2097152 sh (4 MB)
    ushort* Qt  = vb + 2097152;                    // 4 MB
    ushort* Kt  = Qt + 2097152;                    // 4 MB
    ushort* ab  = Kt + 2097152;                    // 4 MB
    ushort* wb1 = ab + 2097152;                    // 393216 sh
    ushort* wb2 = wb1 + 393216;                    // 131072 sh
    ushort* xb  = wb2 + 131072;                    // 8 MB (dead after gemm1)
    float*  pb  = (float*)xb;                      // 16 MB (aliases xb + 8 MB more)

    cvt_bf16<<<192, 256, 0, stream>>>(w_qkv, wb1, 49152);
    cvt_bf16<<<64, 256, 0, stream>>>(w_attn, wb2, 16384);
    transpose_cvt<<<dim3(16, 8, BATCH), 256, 0, stream>>>(x, xb, CIN, HW);

    // QKV projection; epilogue writes Qt/Kt (transposed) and vb (V natural)
    gemm_bt<DQKV, CIN, true, 2>
        <<<dim3(8, 6, BATCH), 256, 0, stream>>>(wb1, xb, b_qkv, vb, Qt, Kt);

    attn_kernel<<<dim3(64, BATCH, 2), 512, 0, stream>>>(vb, Qt, Kt, pb);

    reduce_ab<<<1024, 512, 0, stream>>>(pb, ab);

    gemm_bt<512, 256, false, 0>
        <<<dim3(8, 4, BATCH), 256, 0, stream>>>(wb2, ab, b_attn, out, nullptr, nullptr);
}